// Round 12
// baseline (2366.824 us; speedup 1.0000x reference)
//
#include <hip/hip_runtime.h>
#include <hip/hip_fp16.h>
#include <stdint.h>

// ---------- types ----------
typedef _Float16 half8 __attribute__((ext_vector_type(8)));
typedef _Float16 h2v __attribute__((ext_vector_type(2)));
typedef float f32x16 __attribute__((ext_vector_type(16)));

#define GLD_LDS16(gp, lp)                                                     \
  __builtin_amdgcn_global_load_lds(                                           \
      (const __attribute__((address_space(1))) void*)(gp),                    \
      (__attribute__((address_space(3))) void*)(lp), 16, 0, 0)

// ---------- x convert: fp32 (harness upcast) -> fp16 ----------
__global__ void xcvt_kernel(const float* __restrict__ in, __half* __restrict__ out) {
  const size_t i = ((size_t)blockIdx.x * 256 + threadIdx.x) * 4;
  float4 v = *(const float4*)(in + i);
  __half2* o = (__half2*)(out + i);
  o[0] = __floats2half2_rn(v.x, v.y);
  o[1] = __floats2half2_rn(v.z, v.w);
}

// ---------- repack: qweight [K][N/8] col-packed -> [K/8][N] k-packed ----------
// Output dword for (q, n): nibble of k=8q+t placed at bits 4*(t>>1) + 16*(t&1),
// so that (p >> 4j) & 0x000F000F gives halves (k=2j, k=2j+1).
__global__ void repack_kernel(const int* __restrict__ qw, uint32_t* __restrict__ rp, int P) {
  const int N = P * 8;
  const int n = blockIdx.x * 256 + threadIdx.x;
  const int j8 = n >> 3;
  const int sh = (n & 7) * 4;
  #pragma unroll
  for (int qi = 0; qi < 4; ++qi) {
    const int q = blockIdx.y * 4 + qi;
    const int* src = qw + (size_t)(q * 8) * P + j8;
    uint32_t r = 0;
    #pragma unroll
    for (int t = 0; t < 8; ++t) {
      uint32_t w = ((uint32_t)src[t * P] >> sh) & 15u;
      r |= w << (4 * (t >> 1) + 16 * (t & 1));
    }
    rp[(size_t)q * N + n] = r;
  }
}

// ---------- smz: per (group, col) pack (s_bits, (1024+z)_bits) ----------
__global__ void smz_kernel(const float* __restrict__ sc, const int* __restrict__ qz,
                           uint32_t* __restrict__ smz, int P) {
  const int N = P * 8;
  const int n = blockIdx.x * 256 + threadIdx.x;
  const int g = blockIdx.y;
  uint32_t sbits = __half_as_ushort(__float2half(sc[(size_t)g * N + n]));  // exact
  uint32_t z = ((uint32_t)qz[(size_t)g * P + (n >> 3)] >> ((n & 7) * 4)) & 15u;
  uint32_t hz = 0x6400u | z;  // fp16(1024+z), exact
  smz[(size_t)g * N + n] = sbits | (hz << 16);
}

// ---------- dequant 8 nibbles -> half8 (pk-f16 ops) ----------
union U32H2 { uint32_t u; h2v h; };
__device__ inline h2v bith2(uint32_t u) { U32H2 t; t.u = u; return t.h; }
__device__ inline uint32_t h2bit(h2v h) { U32H2 t; t.h = h; return t.u; }
__device__ inline half8 dequant8(uint32_t p, h2v s, h2v z) {
  union { uint32_t u[4]; half8 v; } r;
  r.u[0] = h2bit((bith2((p & 0x000F000Fu) | 0x64006400u) - z) * s);
  r.u[1] = h2bit((bith2(((p >> 4) & 0x000F000Fu) | 0x64006400u) - z) * s);
  r.u[2] = h2bit((bith2(((p >> 8) & 0x000F000Fu) | 0x64006400u) - z) * s);
  r.u[3] = h2bit((bith2(((p >> 12) & 0x000F000Fu) | 0x64006400u) - z) * s);
  return r.v;  // v_pk_sub_f16 (exact) + v_pk_mul_f16 (1 rounding) per dword
}

// ---------- fused AWQ GEMM (32x32x16, high-occupancy: 4 blocks/CU) ----------
// Block: 128 rows x 2 col-tiles of 64 (tile ct at n0 + ct*T1OFF).
// 4 waves in 2x2: wave (h = wv>>1, q = wv&1) owns rows h*64..+63 and cols
// q*32..+31 of BOTH tiles -> acc = 2ct x 2rf x f32x16 = 64 VGPR.
// Total regs ~120 -> __launch_bounds__(256,4): 4 waves/SIMD, 16 waves/CU.
// LDS 40960 B exactly (A dbuf 2x16KB chunk-major + B dbuf 2x4KB linear)
// -> 4 blocks/CU. Cross-block overlap hides the per-block staging drain,
// so simple 1-ahead staging + __syncthreads suffices (no counted vmcnt).
// A chunk-major [chunk8][row128]x16B: fragment reads 512B contiguous per
// half-wave = conflict-free (R11-proven, SQ_LDS_BANK_CONFLICT = 0).
// B linear [qr8][128 cols]x4B: half-wave reads 128B contiguous (2-way free).
// SMZ: plain-load register prefetch one group ahead (compiler-managed waits).
template <int KDIM, int NW, int T1OFF, int OW, bool SILU, int BXS>
__global__ __launch_bounds__(256, 4) void awq_gemm(const __half* __restrict__ A,
                                                   const uint32_t* __restrict__ RP,
                                                   const uint32_t* __restrict__ SMZ,
                                                   void* __restrict__ OUT) {
  constexpr int ABUF = 128 * 64 * 2;          // 16384 B per A buffer
  constexpr int BBUF = 8 * 128 * 4;           // 4096 B per B buffer
  constexpr int BOFF = 2 * ABUF;              // 32768
  __shared__ __align__(16) unsigned char smem[2 * ABUF + 2 * BBUF];  // 40960

  const int tid = threadIdx.x;
  const int l = tid & 63;
  const int wv = tid >> 6;
  const int h = wv >> 1;        // row half
  const int q = wv & 1;         // col quarter (32 cols per tile)
  const int l31 = l & 31;
  const int lh = l >> 5;        // k-half selector

  const int row0 = blockIdx.y * 128;
  const int n0 = blockIdx.x * BXS;

  // A staging sources, chunk-major dest: thread tid in iteration it stages
  // LDS[it*4096 + tid*16] = chunk (it*2 + tid>>7), row (tid&127).
  const __half* asrc[4];
  #pragma unroll
  for (int it = 0; it < 4; ++it)
    asrc[it] = A + (size_t)(row0 + (tid & 127)) * KDIM + (it * 2 + (tid >> 7)) * 8;

  // B staging source: LDS dword idx = qr*128 + c (c in [0,128): c<64 -> tile0
  // col n0+c, c>=64 -> tile1 col n0+T1OFF+(c-64)). Thread tid covers
  // qr = tid>>5, c = (tid&31)*4 .. +3 (stays within one tile half).
  const int cgrp = (tid & 31) * 4;
  const uint32_t* bsrc = RP + (size_t)(tid >> 5) * NW +
                         (cgrp < 64 ? n0 + cgrp : n0 + T1OFF + (cgrp - 64));

  // SMZ columns for this lane (tile0 / tile1)
  const int scol0 = n0 + q * 32 + l31;
  const int scol1 = n0 + T1OFF + q * 32 + l31;

  f32x16 acc[2][2];  // [ct][rf]
  #pragma unroll
  for (int ct = 0; ct < 2; ++ct)
    #pragma unroll
    for (int rf = 0; rf < 2; ++rf)
      #pragma unroll
      for (int e = 0; e < 16; ++e) acc[ct][rf][e] = 0.f;

  constexpr int NSTEP = KDIM / 64;
  constexpr int NGRP = KDIM / 128;

  // lane-constant LDS offsets
  const int arow16 = (h * 64 + l31) * 16;   // + rf*512 + chunk*2048
  const int bcol0 = (q * 32 + l31) * 4;     // + qr*512 ; tile1 at +256

  // ---- prologue: stage(0) into buf0, prefetch smz group 0 ----
  #pragma unroll
  for (int it = 0; it < 4; ++it)
    GLD_LDS16(asrc[it], &smem[it * 4096 + tid * 16]);
  GLD_LDS16(bsrc, &smem[BOFF + tid * 16]);
  uint32_t su0 = SMZ[scol0];
  uint32_t su1 = SMZ[scol1];

  uint32_t s2[2], z2[2];

  for (int t = 0; t < NSTEP; ++t) {
    const int cur = t & 1;
    __syncthreads();  // drains this wave's stage(t) loads + barrier

    if (t + 1 < NSTEP) {  // stage(t+1) into the other buffer
      #pragma unroll
      for (int it = 0; it < 4; ++it)
        GLD_LDS16(asrc[it] + (size_t)(t + 1) * 64,
                  &smem[(cur ^ 1) * ABUF + it * 4096 + tid * 16]);
      GLD_LDS16(bsrc + (size_t)(t + 1) * 8 * NW,
                &smem[BOFF + (cur ^ 1) * BBUF + tid * 16]);
    }

    if ((t & 1) == 0) {  // group boundary: unpack su, prefetch next group
      uint32_t lo0 = su0 & 0xFFFFu, lo1 = su1 & 0xFFFFu;
      s2[0] = lo0 | (lo0 << 16);
      z2[0] = (su0 & 0xFFFF0000u) | (su0 >> 16);
      s2[1] = lo1 | (lo1 << 16);
      z2[1] = (su1 & 0xFFFF0000u) | (su1 >> 16);
      const int g1 = (t >> 1) + 1;
      if (g1 < NGRP) {
        su0 = SMZ[(size_t)g1 * NW + scol0];
        su1 = SMZ[(size_t)g1 * NW + scol1];
      }
    }

    // B dwords: (ct, kf) -> qr = kf*2+lh, col offset ct*256
    uint32_t bq[2][4];
    const unsigned char* bbase = &smem[BOFF + cur * BBUF];
    #pragma unroll
    for (int ct = 0; ct < 2; ++ct)
      #pragma unroll
      for (int kf = 0; kf < 4; ++kf)
        bq[ct][kf] = *(const uint32_t*)&bbase[(kf * 2 + lh) * 512 + ct * 256 + bcol0];

    const unsigned char* abase = &smem[cur * ABUF];
    #pragma unroll
    for (int kf = 0; kf < 4; ++kf) {
      half8 a[2];
      const int coff = (kf * 2 + lh) * 2048 + arow16;
      a[0] = *(const half8*)(abase + coff);
      a[1] = *(const half8*)(abase + coff + 512);
      #pragma unroll
      for (int ct = 0; ct < 2; ++ct) {
        half8 b = dequant8(bq[ct][kf], bith2(s2[ct]), bith2(z2[ct]));
        acc[ct][0] = __builtin_amdgcn_mfma_f32_32x32x16_f16(a[0], b, acc[ct][0], 0, 0, 0);
        acc[ct][1] = __builtin_amdgcn_mfma_f32_32x32x16_f16(a[1], b, acc[ct][1], 0, 0, 0);
      }
    }
  }

  // epilogue: C/D layout: col = l31, row = rf*32 + (reg&3) + 8*(reg>>2) + 4*lh
  if (SILU) {
    __half* O = (__half*)OUT;
    #pragma unroll
    for (int rf = 0; rf < 2; ++rf)
      #pragma unroll
      for (int reg = 0; reg < 16; ++reg) {
        int row = row0 + h * 64 + rf * 32 + (reg & 3) + 8 * (reg >> 2) + 4 * lh;
        int col = n0 + q * 32 + l31;
        float gf = __half2float(__float2half(acc[0][rf][reg]));  // gate fp16 cast
        float uf = __half2float(__float2half(acc[1][rf][reg]));  // up fp16 cast
        float sig = 1.f / (1.f + __expf(-gf));
        float sil = __half2float(__float2half(gf * sig));        // silu fp16 cast
        O[(size_t)row * OW + col] = __float2half(sil * uf);      // intermediate fp16
      }
  } else {
    float* O = (float*)OUT;
    #pragma unroll
    for (int ct = 0; ct < 2; ++ct)
      #pragma unroll
      for (int rf = 0; rf < 2; ++rf)
        #pragma unroll
        for (int reg = 0; reg < 16; ++reg) {
          int row = row0 + h * 64 + rf * 32 + (reg & 3) + 8 * (reg >> 2) + 4 * lh;
          int col = n0 + ct * T1OFF + q * 32 + l31;
          O[(size_t)row * OW + col] = __half2float(__float2half(acc[ct][rf][reg]));
        }
  }
}

// ---------- launch ----------
// Workspace phase-aliasing (stay under round-1-proven-safe 263,397,376 B):
//   phase 1 (through GEMM1): interm | rp_gu | smz_gu | xh   = 256,688,128 B
//   phase 2 (after GEMM1):   interm | rp_dn | smz_dn        = 191,258,624 B
extern "C" void kernel_launch(void* const* d_in, const int* in_sizes, int n_in,
                              void* d_out, int out_size, void* d_ws, size_t ws_size,
                              hipStream_t stream) {
  const float* x_f32 = (const float*)d_in[0];          // harness upcasts fp16 -> fp32
  const int* qw_gu = (const int*)d_in[1];
  const int* qz_gu = (const int*)d_in[2];
  const float* sc_gu = (const float*)d_in[3];          // fp32 (upcast)
  const int* qw_dn = (const int*)d_in[4];
  const int* qz_dn = (const int*)d_in[5];
  const float* sc_dn = (const float*)d_in[6];          // fp32 (upcast)

  char* ws = (char*)d_ws;
  __half* interm   = (__half*)ws;                      // 155,189,248
  uint32_t* rp_gu  = (uint32_t*)(ws + 155189248ull);   // 67,895,296
  uint32_t* smz_gu = (uint32_t*)(ws + 223084544ull);   // 4,243,456
  __half* xh       = (__half*)(ws + 227328000ull);     // 29,360,128
  uint32_t* rp_dn  = (uint32_t*)(ws + 155189248ull);   // aliases rp_gu
  uint32_t* smz_dn = (uint32_t*)(ws + 189136896ull);

  // ---- phase 1: prep + GEMM1 ----
  xcvt_kernel<<<14336, 256, 0, stream>>>(x_f32, xh);
  repack_kernel<<<dim3(148, 112), 256, 0, stream>>>(qw_gu, rp_gu, 4736);
  smz_kernel<<<dim3(148, 28), 256, 0, stream>>>(sc_gu, qz_gu, smz_gu, 4736);

  // GEMM1: block = 128 rows x (64 gate cols at n0) + (64 up cols at n0+18944)
  awq_gemm<3584, 37888, 18944, 18944, true, 64>
      <<<dim3(296, 32), 256, 0, stream>>>(xh, rp_gu, smz_gu, (void*)interm);

  // ---- phase 2: prep + GEMM2 (aliased scratch) ----
  repack_kernel<<<dim3(14, 592), 256, 0, stream>>>(qw_dn, rp_dn, 448);
  smz_kernel<<<dim3(14, 148), 256, 0, stream>>>(sc_dn, qz_dn, smz_dn, 448);

  // GEMM2: block = 128 rows x 128 cols (two 64-col tiles at +0/+64)
  awq_gemm<18944, 3584, 64, 3584, false, 128>
      <<<dim3(28, 32), 256, 0, stream>>>(interm, rp_dn, smz_dn, d_out);
}

// Round 13
// 1630.003 us; speedup vs baseline: 1.4520x; 1.4520x over previous
//
#include <hip/hip_runtime.h>
#include <hip/hip_fp16.h>
#include <stdint.h>

// ---------- types ----------
typedef _Float16 half8 __attribute__((ext_vector_type(8)));
typedef _Float16 h2v __attribute__((ext_vector_type(2)));
typedef float f32x4 __attribute__((ext_vector_type(4)));

#define GLD_LDS16(gp, lp)                                                     \
  __builtin_amdgcn_global_load_lds(                                           \
      (const __attribute__((address_space(1))) void*)(gp),                    \
      (__attribute__((address_space(3))) void*)(lp), 16, 0, 0)
#define GLD_LDS4(gp, lp)                                                      \
  __builtin_amdgcn_global_load_lds(                                           \
      (const __attribute__((address_space(1))) void*)(gp),                    \
      (__attribute__((address_space(3))) void*)(lp), 4, 0, 0)

// ---------- x convert: fp32 (harness upcast) -> fp16 ----------
__global__ void xcvt_kernel(const float* __restrict__ in, __half* __restrict__ out) {
  const size_t i = ((size_t)blockIdx.x * 256 + threadIdx.x) * 4;
  float4 v = *(const float4*)(in + i);
  __half2* o = (__half2*)(out + i);
  o[0] = __floats2half2_rn(v.x, v.y);
  o[1] = __floats2half2_rn(v.z, v.w);
}

// ---------- repack: qweight [K][N/8] col-packed -> [K/8][N] k-packed ----------
// Output dword for (q, n): nibble of k=8q+t placed at bits 4*(t>>1) + 16*(t&1),
// so that (p >> 4j) & 0x000F000F gives halves (k=2j, k=2j+1).
__global__ void repack_kernel(const int* __restrict__ qw, uint32_t* __restrict__ rp, int P) {
  const int N = P * 8;
  const int n = blockIdx.x * 256 + threadIdx.x;
  const int j8 = n >> 3;
  const int sh = (n & 7) * 4;
  #pragma unroll
  for (int qi = 0; qi < 4; ++qi) {
    const int q = blockIdx.y * 4 + qi;
    const int* src = qw + (size_t)(q * 8) * P + j8;
    uint32_t r = 0;
    #pragma unroll
    for (int t = 0; t < 8; ++t) {
      uint32_t w = ((uint32_t)src[t * P] >> sh) & 15u;
      r |= w << (4 * (t >> 1) + 16 * (t & 1));
    }
    rp[(size_t)q * N + n] = r;
  }
}

// ---------- smz: per (group, col) pack (s_bits, (1024+z)_bits) ----------
__global__ void smz_kernel(const float* __restrict__ sc, const int* __restrict__ qz,
                           uint32_t* __restrict__ smz, int P) {
  const int N = P * 8;
  const int n = blockIdx.x * 256 + threadIdx.x;
  const int g = blockIdx.y;
  uint32_t sbits = __half_as_ushort(__float2half(sc[(size_t)g * N + n]));  // exact
  uint32_t z = ((uint32_t)qz[(size_t)g * P + (n >> 3)] >> ((n & 7) * 4)) & 15u;
  uint32_t hz = 0x6400u | z;  // fp16(1024+z), exact
  smz[(size_t)g * N + n] = sbits | (hz << 16);
}

// ---------- dequant 8 nibbles -> half8 (pk-f16 ops) ----------
union U32H2 { uint32_t u; h2v h; };
__device__ inline h2v bith2(uint32_t u) { U32H2 t; t.u = u; return t.h; }
__device__ inline uint32_t h2bit(h2v h) { U32H2 t; t.h = h; return t.u; }
__device__ inline half8 dequant8(uint32_t p, h2v s, h2v z) {
  union { uint32_t u[4]; half8 v; } r;
  r.u[0] = h2bit((bith2((p & 0x000F000Fu) | 0x64006400u) - z) * s);
  r.u[1] = h2bit((bith2(((p >> 4) & 0x000F000Fu) | 0x64006400u) - z) * s);
  r.u[2] = h2bit((bith2(((p >> 8) & 0x000F000Fu) | 0x64006400u) - z) * s);
  r.u[3] = h2bit((bith2(((p >> 12) & 0x000F000Fu) | 0x64006400u) - z) * s);
  return r.v;  // v_pk_sub_f16 (exact) + v_pk_mul_f16 (1 rounding) per dword
}

// ---------- fused AWQ GEMM (16x16x32, 8-wave tall-narrow, 4 waves/SIMD) ----------
// Block: 512 threads = 8 waves. 128 rows x 2 tiles of 128 cols
// (tile tl at n0 + tl*T1OFF, n0 = blockIdx.x * BXS).
// Wave wv owns 128 rows x cols [wv*16, +16) of BOTH tiles:
//   dequant = 2kk x 2tl = 4 dequant8 / K-step feeding 32 MFMAs (1:8 ratio),
//   acc = 2 tiles x 8 mf x f32x4 = 64 VGPR -> ~110 total -> 4 waves/SIMD.
// LDS 75776 B -> 2 blocks/CU -> 16 waves/CU (Occupancy ~42%).
// A: R7-proven row-major XOR-swizzled layout (slot c at row m holds k-chunk
// c^(m&7)); measured 0 bank conflicts for this fragment read.
// B: R7-proven layout, dword (qr, c) holds RP col (c ^ S(qr)),
// S(qr) = ((qr&1)<<4)|((qr>>1)<<2); 2-way reads = free.
// SMZ: double-buffered 1KB in LDS; ALL 8 waves issue the same GLD4 (waves
// 4-7 duplicate waves 0-3's data) so every wave's VMEM batch count is equal.
// Triple-buffered A/B staging; one s_barrier per K-step preceded by COUNTED
// s_waitcnt: batch(k) = 2xA + 1xB (+1 smz if k even) -> steady wait
// vmcnt(3) (t even) / vmcnt(4) (t odd), vmcnt(0) on the last step.
template <int KDIM, int NW, int T1OFF, int OW, bool SILU, int BXS>
__global__ __launch_bounds__(512, 4) void awq_gemm(const __half* __restrict__ A,
                                                   const uint32_t* __restrict__ RP,
                                                   const uint32_t* __restrict__ SMZ,
                                                   void* __restrict__ OUT) {
  constexpr int ABUF = 128 * 64 * 2;          // 16384 B per A buffer
  constexpr int BBUF = 8 * 256 * 4;           // 8192 B per B buffer (2 tiles)
  constexpr int BOFF = 3 * ABUF;              // 49152
  constexpr int ZOFF = BOFF + 3 * BBUF;       // 73728; smz dbuf 2 x 1024
  __shared__ __align__(16) unsigned char smem[ZOFF + 2048];  // 75776

  const int tid = threadIdx.x;
  const int l = tid & 63;
  const int wv = tid >> 6;      // 0..7
  const int l15 = l & 15;
  const int l4 = l >> 4;
  const int wc = wv * 16;       // wave's col base within the 128-col tile

  const int row0 = blockIdx.y * 128;
  const int n0 = blockIdx.x * BXS;

  // A staging sources (2 iters x 512 thr x 16B = 16KB):
  // iter it: m = it*64 + tid>>3, slot cs = tid&7 holds chunk cs^(m&7)
  const __half* asrc[2];
  #pragma unroll
  for (int it = 0; it < 2; ++it) {
    int m = it * 64 + (tid >> 3);
    int cs = tid & 7;
    int kc = cs ^ (m & 7);
    asrc[it] = A + (size_t)(row0 + m) * KDIM + kc * 8;
  }

  // B staging source (1 iter x 512 thr x 16B = 8KB):
  // dword (qr = tid>>6, c = (tid&63)*4 ..+3) holds RP col map(c ^ S(qr))
  const uint32_t* bsrc;
  {
    int qr = tid >> 6;
    int c4 = (tid & 63) * 4;
    int S = ((qr & 1) << 4) | ((qr >> 1) << 2);
    int cS = c4 ^ S;
    int bcol = (cS < 128) ? n0 + cS : n0 + T1OFF + (cS - 128);
    bsrc = RP + (size_t)qr * NW + bcol;
  }

  // SMZ staging source: wave w3 = wv&3 covers cols c = w3*64 + lane (0..255)
  const uint32_t* zsrc;
  {
    int w3 = wv & 3;
    int zc = w3 * 64 + l;
    zsrc = SMZ + ((zc < 128) ? n0 + zc : n0 + T1OFF + (zc - 128));
  }
  const int zdst = ZOFF + (wv & 3) * 256;  // + zb*1024 (wave-uniform)

  f32x4 acc0[8], acc1[8];
  const f32x4 zero4 = {0.f, 0.f, 0.f, 0.f};
  #pragma unroll
  for (int mf = 0; mf < 8; ++mf) { acc0[mf] = zero4; acc1[mf] = zero4; }

  uint32_t s2[2], z2[2];
  constexpr int NSTEP = KDIM / 64;

  // ---- prologue: batch(0) [2A,B,smz g0] then batch(1) [2A,B] ----
  #pragma unroll
  for (int it = 0; it < 2; ++it)
    GLD_LDS16(asrc[it], &smem[it * 8192 + tid * 16]);
  GLD_LDS16(bsrc, &smem[BOFF + tid * 16]);
  GLD_LDS4(zsrc, &smem[zdst]);
  #pragma unroll
  for (int it = 0; it < 2; ++it)
    GLD_LDS16(asrc[it] + 64, &smem[ABUF + it * 8192 + tid * 16]);
  GLD_LDS16(bsrc + (size_t)8 * NW, &smem[BOFF + BBUF + tid * 16]);

  int cur = 0, stg = 2;  // buf(t%3), buf((t+2)%3)
  for (int t = 0; t < NSTEP; ++t) {
    // counted wait: drain batch(t); batch(t+1) stays in flight
    if (t == NSTEP - 1)      asm volatile("s_waitcnt vmcnt(0)" ::: "memory");
    else if (t & 1)          asm volatile("s_waitcnt vmcnt(4)" ::: "memory");
    else                     asm volatile("s_waitcnt vmcnt(3)" ::: "memory");
    __builtin_amdgcn_s_barrier();

    // issue batch(t+2) into buf stg
    if (t + 2 < NSTEP) {
      #pragma unroll
      for (int it = 0; it < 2; ++it)
        GLD_LDS16(asrc[it] + (size_t)(t + 2) * 64,
                  &smem[stg * ABUF + it * 8192 + tid * 16]);
      GLD_LDS16(bsrc + (size_t)(t + 2) * 8 * NW, &smem[BOFF + stg * BBUF + tid * 16]);
      if (((t + 2) & 1) == 0) {  // smz for group (t+2)/2 into zbuf (g&1)
        const int g = (t + 2) >> 1;
        GLD_LDS4(zsrc + (size_t)g * NW, &smem[zdst + (g & 1) * 1024]);
      }
    }

    if ((t & 1) == 0) {  // group boundary: unpack s/z from zbuf ((t>>1)&1)
      const uint32_t* zl = (const uint32_t*)&smem[ZOFF + ((t >> 1) & 1) * 1024];
      uint32_t u0 = zl[wc + l15];
      uint32_t u1 = zl[128 + wc + l15];
      uint32_t lo0 = u0 & 0xFFFFu, lo1 = u1 & 0xFFFFu;
      s2[0] = lo0 | (lo0 << 16);
      z2[0] = (u0 & 0xFFFF0000u) | (u0 >> 16);
      s2[1] = lo1 | (lo1 << 16);
      z2[1] = (u1 & 0xFFFF0000u) | (u1 >> 16);
    }

    // B dwords (read swizzle matches staged source swizzle)
    uint32_t bq[2][2];  // [kk][tl]
    const uint32_t* bdw = (const uint32_t*)&smem[BOFF + cur * BBUF];
    #pragma unroll
    for (int kk = 0; kk < 2; ++kk) {
      const int Sl = ((l4 & 1) << 4) | (kk << 3) | ((l4 >> 1) << 2);
      const int qrow = (kk * 4 + l4) * 256;
      bq[kk][0] = bdw[qrow + ((wc + l15) ^ Sl)];
      bq[kk][1] = bdw[qrow + ((128 + wc + l15) ^ Sl)];
    }

    const unsigned char* abase = &smem[cur * ABUF];
    __builtin_amdgcn_s_setprio(1);
    #pragma unroll
    for (int kk = 0; kk < 2; ++kk) {
      half8 b0 = dequant8(bq[kk][0], bith2(s2[0]), bith2(z2[0]));
      half8 b1 = dequant8(bq[kk][1], bith2(s2[1]), bith2(z2[1]));
      const int chunkoff = ((kk * 4 + l4) ^ (l15 & 7)) * 16;
      #pragma unroll
      for (int mf = 0; mf < 8; ++mf) {
        half8 a = *(const half8*)(abase + (mf * 16 + l15) * 128 + chunkoff);
        acc0[mf] = __builtin_amdgcn_mfma_f32_16x16x32_f16(a, b0, acc0[mf], 0, 0, 0);
        acc1[mf] = __builtin_amdgcn_mfma_f32_16x16x32_f16(a, b1, acc1[mf], 0, 0, 0);
      }
    }
    __builtin_amdgcn_s_setprio(0);

    cur = (cur == 2) ? 0 : cur + 1;
    stg = (stg == 2) ? 0 : stg + 1;
  }

  // epilogue: C/D: col = l15, row = mf*16 + l4*4 + r
  if (SILU) {
    __half* O = (__half*)OUT;
    #pragma unroll
    for (int mf = 0; mf < 8; ++mf)
      #pragma unroll
      for (int r = 0; r < 4; ++r) {
        int row = row0 + mf * 16 + l4 * 4 + r;
        int col = n0 + wc + l15;
        float gf = __half2float(__float2half(acc0[mf][r]));  // gate fp16 cast
        float uf = __half2float(__float2half(acc1[mf][r]));  // up fp16 cast
        float sig = 1.f / (1.f + __expf(-gf));
        float sil = __half2float(__float2half(gf * sig));    // silu fp16 cast
        O[(size_t)row * OW + col] = __float2half(sil * uf);  // intermediate fp16
      }
  } else {
    float* O = (float*)OUT;
    #pragma unroll
    for (int mf = 0; mf < 8; ++mf)
      #pragma unroll
      for (int r = 0; r < 4; ++r) {
        int row = row0 + mf * 16 + l4 * 4 + r;
        int col0 = n0 + wc + l15;
        int col1 = n0 + T1OFF + wc + l15;
        O[(size_t)row * OW + col0] = __half2float(__float2half(acc0[mf][r]));
        O[(size_t)row * OW + col1] = __half2float(__float2half(acc1[mf][r]));
      }
  }
}

// ---------- launch ----------
// Workspace phase-aliasing (stay under round-1-proven-safe 263,397,376 B):
//   phase 1 (through GEMM1): interm | rp_gu | smz_gu | xh   = 256,688,128 B
//   phase 2 (after GEMM1):   interm | rp_dn | smz_dn        = 191,258,624 B
extern "C" void kernel_launch(void* const* d_in, const int* in_sizes, int n_in,
                              void* d_out, int out_size, void* d_ws, size_t ws_size,
                              hipStream_t stream) {
  const float* x_f32 = (const float*)d_in[0];          // harness upcasts fp16 -> fp32
  const int* qw_gu = (const int*)d_in[1];
  const int* qz_gu = (const int*)d_in[2];
  const float* sc_gu = (const float*)d_in[3];          // fp32 (upcast)
  const int* qw_dn = (const int*)d_in[4];
  const int* qz_dn = (const int*)d_in[5];
  const float* sc_dn = (const float*)d_in[6];          // fp32 (upcast)

  char* ws = (char*)d_ws;
  __half* interm   = (__half*)ws;                      // 155,189,248
  uint32_t* rp_gu  = (uint32_t*)(ws + 155189248ull);   // 67,895,296
  uint32_t* smz_gu = (uint32_t*)(ws + 223084544ull);   // 4,243,456
  __half* xh       = (__half*)(ws + 227328000ull);     // 29,360,128
  uint32_t* rp_dn  = (uint32_t*)(ws + 155189248ull);   // aliases rp_gu
  uint32_t* smz_dn = (uint32_t*)(ws + 189136896ull);

  // ---- phase 1: prep + GEMM1 ----
  xcvt_kernel<<<14336, 256, 0, stream>>>(x_f32, xh);
  repack_kernel<<<dim3(148, 112), 256, 0, stream>>>(qw_gu, rp_gu, 4736);
  smz_kernel<<<dim3(148, 28), 256, 0, stream>>>(sc_gu, qz_gu, smz_gu, 4736);

  // GEMM1: block = 128 rows x (128 gate cols at n0 + 128 up cols at n0+18944)
  awq_gemm<3584, 37888, 18944, 18944, true, 128>
      <<<dim3(148, 32), 512, 0, stream>>>(xh, rp_gu, smz_gu, (void*)interm);

  // ---- phase 2: prep + GEMM2 (aliased scratch) ----
  repack_kernel<<<dim3(14, 592), 256, 0, stream>>>(qw_dn, rp_dn, 448);
  smz_kernel<<<dim3(14, 148), 256, 0, stream>>>(sc_dn, qz_dn, smz_dn, 448);

  // GEMM2: block = 128 rows x 256 cols (two 128-col tiles at +0/+128)
  awq_gemm<18944, 3584, 128, 3584, false, 256>
      <<<dim3(14, 32), 512, 0, stream>>>(interm, rp_dn, smz_dn, d_out);
}